// Round 4
// baseline (2393.072 us; speedup 1.0000x reference)
//
#include <hip/hip_runtime.h>
#include <cmath>

#define BROWS 16384
#define CDIM  1024
#define NIT   16

typedef __attribute__((ext_vector_type(8))) short short8;
typedef __attribute__((ext_vector_type(4))) short short4v;
typedef __attribute__((ext_vector_type(4))) float floatx4;

__device__ __forceinline__ unsigned short f2bf(float f) {
  union { float f; unsigned u; } x; x.f = f;
  unsigned r = x.u + 0x7fffu + ((x.u >> 16) & 1u);  // RNE
  return (unsigned short)(r >> 16);
}
__device__ __forceinline__ float bf2f(unsigned short h) {
  union { float f; unsigned u; } x; x.u = ((unsigned)h) << 16;
  return x.f;
}

// ---- one-time prep: weights fp32 -> bf16, both [n][k] and transposed ----
__global__ void prep_weights(const float* __restrict__ W1, const float* __restrict__ W2,
                             const float* __restrict__ W3,
                             unsigned short* __restrict__ Wb, unsigned short* __restrict__ Wt) {
  int idx = blockIdx.x * 256 + threadIdx.x;   // 0 .. 3*2^20-1
  int m = idx >> 20;
  int r = (idx >> 10) & 1023;
  int c = idx & 1023;
  const float* W = (m == 0) ? W1 : ((m == 1) ? W2 : W3);
  unsigned short b = f2bf(W[r * CDIM + c]);
  Wb[idx] = b;                                // forward: B[n][k] = W[n][k]
  Wt[(m << 20) + c * CDIM + r] = b;           // backward: B[n][k] = W[k][n]
}

__global__ void conv_inputs(const float* __restrict__ y, const float* __restrict__ v,
                            unsigned short* __restrict__ ybf, unsigned short* __restrict__ wbf,
                            float* __restrict__ inner) {
  int i = (blockIdx.x * 256 + threadIdx.x) * 4;   // vectorized x4
  floatx4 yv = *(const floatx4*)(y + i);
  floatx4 vv = *(const floatx4*)(v + i);
  short4v a, b;
#pragma unroll
  for (int r = 0; r < 4; r++) { a[r] = (short)f2bf(yv[r]); b[r] = (short)f2bf(vv[r]); }
  *(short4v*)(ybf + i) = a;
  *(short4v*)(wbf + i) = b;
  if (i < NIT * BROWS) *(floatx4*)(inner + i) = floatx4{0.f, 0.f, 0.f, 0.f};
}

// v fp32 -> bf16, into the (now free) ybf buffer; runs after GEMM1 on stream
__global__ void conv_v(const float* __restrict__ v, unsigned short* __restrict__ vb) {
  int i = (blockIdx.x * 256 + threadIdx.x) * 8;
  floatx4 a = *(const floatx4*)(v + i);
  floatx4 b = *(const floatx4*)(v + i + 4);
  short8 o;
#pragma unroll
  for (int r = 0; r < 4; r++) { o[r] = (short)f2bf(a[r]); o[r + 4] = (short)f2bf(b[r]); }
  *(short8*)(vb + i) = o;
}

// ---- GEMM: C[m,n] = sum_k A[m,k]*B[n,k]; A: M x K bf16, B: N x K bf16 ----
// 256x256 tile, BK=64, 512 threads (8 waves = 2M x 4N), 1 block/CU, grid=256.
// 3 phases/K-tile (P0: 12 ds_reads + 4 stages + 16 MFMA; P1: 4 stages + 16 MFMA;
// P2: 8 ds_reads + 32-MFMA cluster + counted vmcnt(2)). Derivative buffers are
// GONE: MODE 0 stores only the activation; MODE 2 computes elu' on the fly.
// MODE 0: FWD   outB = bf16(elu(acc+bias))
// MODE 1: FWD3  outZ = acc + bias + yin   (fp32)
// MODE 2: BWD   outB = bf16(acc * elu'(Dm))   (Dm = stored ACTIVATION)
// MODE 3: BWD3  outB = bf16(acc); inner[row] += sum_n acc*vin
template <int MODE>
__global__ __launch_bounds__(512, 2)
void gemm_k(const unsigned short* __restrict__ A,
            const unsigned short* __restrict__ Bm,
            const float* __restrict__ bias,
            const float* __restrict__ yin,
            const unsigned short* __restrict__ Dm,
            const unsigned short* __restrict__ vin,
            unsigned short* __restrict__ outB,
            float* __restrict__ outZ,
            float* __restrict__ inner) {
  constexpr int K = CDIM;
  // 128 KiB: 2 buffers x (A 256x64 + B 256x64) bf16, as 4 half-tiles of 128x64
  __shared__ unsigned short smem[65536];

  const int t = threadIdx.x;
  // 256 blocks = 64 m-tiles x 4 n-tiles; XCD swizzle: XCD x owns m-slab x (8 m-tiles),
  // and the 4 n-blocks of one m-tile land on the SAME XCD (A-panel L2 reuse).
  const int wg = (blockIdx.x & 7) * 32 + (blockIdx.x >> 3);
  const int m0 = (wg >> 2) * 256;
  const int n0 = (wg & 3) * 256;

  const int wave = t >> 6, lane = t & 63;
  const int quad = lane >> 4, ln = lane & 15;
  const int wm = wave >> 2;          // 0..1 : which 128-row half of the tile
  const int wn = wave & 3;           // 0..3 : which 64-col strip

  // staging: thread t loads 16B from global, LDS dest is lane-linear (t*16B);
  // the XOR swizzle lives in the GLOBAL column (global_load_lds can't scatter).
  const int srow = t >> 3;                              // 0..63
  const int gcolE = ((t & 7) ^ (srow & 7)) * 8;         // swizzled k-offset (elems)
  const unsigned short* gA = A + (size_t)(m0 + srow) * K + gcolE;
  const unsigned short* gB = Bm + (size_t)(n0 + srow) * K + gcolE;
  const int ldE = t * 8;                                // elems within half-tile

  // fragment-read swizzle (row&7 == ln&7 for all fragments)
  const int swzE = (ln & 7) << 3;
  const int aHalf = wm * 8192;                  // elems: A-top / A-bot
  const int bHalf = 16384 + (wn >> 1) * 8192;   // B-top / B-bot
  const int bRow = (wn & 1) * 64;               // 64-row slice within B half

#define GLL(gp, le)                                                                       \
  __builtin_amdgcn_global_load_lds((const __attribute__((address_space(1))) void*)(gp),   \
                                   (__attribute__((address_space(3))) void*)&smem[le], 16, 0, 0)
  // A-firsts: rows 0-63 of each 128-half (what aF0 reads need)
#define STAGE_A1(k0, pb) do {                                                             \
    GLL(gA + (k0),                    (pb) + ldE);                                        \
    GLL(gA + (size_t)128 * K + (k0),  (pb) + 8192 + ldE);                                 \
  } while (0)
  // A-seconds: rows 64-127 of each half (aF1 reads; issued LAST -> counted waits)
#define STAGE_A2(k0, pb) do {                                                             \
    GLL(gA + (size_t)64 * K + (k0),   (pb) + 4096 + ldE);                                 \
    GLL(gA + (size_t)192 * K + (k0),  (pb) + 8192 + 4096 + ldE);                          \
  } while (0)
#define STAGE_B2a(k0, pb) do {                                                            \
    GLL(gB + (k0),                    (pb) + 16384 + ldE);                                \
    GLL(gB + (size_t)64 * K + (k0),   (pb) + 16384 + 4096 + ldE);                         \
  } while (0)
#define STAGE_B2b(k0, pb) do {                                                            \
    GLL(gB + (size_t)128 * K + (k0),  (pb) + 16384 + 8192 + ldE);                         \
    GLL(gB + (size_t)192 * K + (k0),  (pb) + 16384 + 8192 + 4096 + ldE);                  \
  } while (0)

  floatx4 acc[8][4];
#pragma unroll
  for (int i = 0; i < 8; ++i)
#pragma unroll
    for (int j = 0; j < 4; ++j) acc[i][j] = {0.f, 0.f, 0.f, 0.f};

  short8 aF[4][2];   // current 64-row half of A fragments
  short8 bF[4][2];   // ALL B fragments for the wave's 64 cols (held whole K-tile)

  // prologue: stage buf0 in steady-state order; A-seconds may stay in flight
  STAGE_A1(0, 0); STAGE_B2a(0, 0); STAGE_B2b(0, 0); STAGE_A2(0, 0);
  asm volatile("s_waitcnt vmcnt(2)" ::: "memory");
  __builtin_amdgcn_s_barrier();

#define READ_A(qm_, bufE_) do {                                                           \
    _Pragma("unroll") for (int mi = 0; mi < 4; ++mi)                                      \
    _Pragma("unroll") for (int ks = 0; ks < 2; ++ks)                                      \
      aF[mi][ks] = *(const short8*)&smem[(bufE_) + aHalf + ((qm_) * 64 + mi * 16 + ln) * 64 \
                                         + ((ks * 32 + quad * 8) ^ swzE)];                \
  } while (0)
#define READ_B2(n0_, bufE_) do {                                                          \
    _Pragma("unroll") for (int ni = (n0_); ni < (n0_) + 2; ++ni)                          \
    _Pragma("unroll") for (int ks = 0; ks < 2; ++ks)                                      \
      bF[ni][ks] = *(const short8*)&smem[(bufE_) + bHalf + (bRow + ni * 16 + ln) * 64     \
                                         + ((ks * 32 + quad * 8) ^ swzE)];                \
  } while (0)
#define MFMA_Q(qm_, qn_) do {                                                             \
    _Pragma("unroll") for (int mi = 0; mi < 4; ++mi)                                      \
    _Pragma("unroll") for (int ni = 0; ni < 2; ++ni)                                      \
    _Pragma("unroll") for (int ks = 0; ks < 2; ++ks)                                      \
      acc[(qm_) * 4 + mi][(qn_) * 2 + ni] = __builtin_amdgcn_mfma_f32_16x16x32_bf16(      \
          aF[mi][ks], bF[(qn_) * 2 + ni][ks], acc[(qm_) * 4 + mi][(qn_) * 2 + ni], 0, 0, 0); \
  } while (0)

#pragma unroll 2
  for (int kt = 0; kt < 16; ++kt) {
    const int bufE = (kt & 1) * 32768;
    const int nxtE = bufE ^ 32768;
    const int kn = (kt + 1) * 64;
    const bool st = (kt < 15);

    // ---- P0: reads aF0+bF0 | stage next A-firsts + B-top ----
    READ_A(0, bufE);
    READ_B2(0, bufE);
    if (st) { STAGE_A1(kn, nxtE); STAGE_B2a(kn, nxtE); }
    __builtin_amdgcn_s_barrier();
    asm volatile("s_waitcnt lgkmcnt(0)" ::: "memory");
    __builtin_amdgcn_sched_barrier(0);
    __builtin_amdgcn_s_setprio(1);
    READ_B2(2, bufE);                 // bF1 issues under P0's MFMA (distinct regs)
    MFMA_Q(0, 0);
    __builtin_amdgcn_s_setprio(0);
    __builtin_amdgcn_sched_barrier(0);
    __builtin_amdgcn_s_barrier();

    // ---- P1: stage next B-bottom + A-seconds (youngest loads) ----
    if (st) { STAGE_B2b(kn, nxtE); STAGE_A2(kn, nxtE); }
    __builtin_amdgcn_s_barrier();
    asm volatile("s_waitcnt lgkmcnt(0)" ::: "memory");   // bF1 (mostly retired already)
    __builtin_amdgcn_sched_barrier(0);
    __builtin_amdgcn_s_setprio(1);
    MFMA_Q(0, 1);
    __builtin_amdgcn_s_setprio(0);
    __builtin_amdgcn_sched_barrier(0);
    // retire cur-buf A-seconds (2 oldest); keep next-buf loads (<=8) in flight
    if (kt == 15) asm volatile("s_waitcnt vmcnt(0)" ::: "memory");
    else          asm volatile("s_waitcnt vmcnt(8)" ::: "memory");
    __builtin_amdgcn_s_barrier();

    // ---- P2: reads aF1 | 32-MFMA cluster | counted drain of next A1+B ----
    READ_A(1, bufE);
    __builtin_amdgcn_s_barrier();
    asm volatile("s_waitcnt lgkmcnt(0)" ::: "memory");
    __builtin_amdgcn_sched_barrier(0);
    __builtin_amdgcn_s_setprio(1);
    MFMA_Q(1, 0);
    MFMA_Q(1, 1);
    __builtin_amdgcn_s_setprio(0);
    __builtin_amdgcn_sched_barrier(0);
    if (st) asm volatile("s_waitcnt vmcnt(2)" ::: "memory");  // A1+B landed; A2 flies on
    __builtin_amdgcn_s_barrier();
  }
#undef MFMA_Q
#undef READ_A
#undef READ_B2
#undef STAGE_A1
#undef STAGE_A2
#undef STAGE_B2a
#undef STAGE_B2b
#undef GLL

  // ---- epilogue: 2 rounds of 128 rows through LDS (stride 260: conflict-free
  // scalar writes, 8B-aligned reads), then coalesced global I/O ----
  unsigned short* Ct = smem;
  const int colW = wn * 64 + ln;
  float bv[4];
  if (MODE == 0) {
#pragma unroll
    for (int NI = 0; NI < 4; ++NI) bv[NI] = bias[n0 + colW + NI * 16];
  }
  for (int h = 0; h < 2; ++h) {
    if (wm == h) {
#pragma unroll
      for (int MI = 0; MI < 8; ++MI)
#pragma unroll
        for (int NI = 0; NI < 4; ++NI)
#pragma unroll
          for (int r = 0; r < 4; ++r) {
            float pv = acc[MI][NI][r];
            if (MODE == 0) {
              pv += bv[NI];
              pv = (pv > 0.f) ? pv : expm1f(pv);
            }
            Ct[(MI * 16 + quad * 4 + r) * 260 + colW + NI * 16] = f2bf(pv);
          }
    }
    __syncthreads();
    const int rr = t >> 5;            // 0..15
    const int cc = (t & 31) * 8;      // 0..248
#pragma unroll
    for (int it = 0; it < 8; ++it) {
      const int lr = it * 16 + rr;
      short4v v0 = *(const short4v*)&Ct[lr * 260 + cc];
      short4v v1 = *(const short4v*)&Ct[lr * 260 + cc + 4];
      short8 val;
#pragma unroll
      for (int i = 0; i < 4; ++i) { val[i] = v0[i]; val[i + 4] = v1[i]; }
      const size_t o = (size_t)(m0 + h * 128 + lr) * CDIM + (n0 + cc);
      if (MODE == 0) {
        *(short8*)&outB[o] = val;               // activation only; elu' derived by consumer
      } else if (MODE == 1) {
        const floatx4 y0 = *(const floatx4*)&yin[o];
        const floatx4 y1 = *(const floatx4*)&yin[o + 4];
        const floatx4 b0 = *(const floatx4*)&bias[n0 + cc];
        const floatx4 b1 = *(const floatx4*)&bias[n0 + cc + 4];
        floatx4 z0, z1;
#pragma unroll
        for (int i = 0; i < 4; ++i) {
          z0[i] = bf2f((unsigned short)val[i]) + b0[i] + y0[i];
          z1[i] = bf2f((unsigned short)val[i + 4]) + b1[i] + y1[i];
        }
        *(floatx4*)&outZ[o] = z0;
        *(floatx4*)&outZ[o + 4] = z1;
      } else if (MODE == 2) {
        short8 d = *(const short8*)&Dm[o];      // d = stored ACTIVATION h
        short8 ov;
#pragma unroll
        for (int i = 0; i < 8; ++i) {
          float e = bf2f((unsigned short)d[i]);
          float dp = (e > 0.f) ? 1.f : e + 1.f; // elu'(h) in fp32
          ov[i] = (short)f2bf(bf2f((unsigned short)val[i]) * dp);
        }
        *(short8*)&outB[o] = ov;
      } else {  // MODE 3
        *(short8*)&outB[o] = val;
        short8 vv = *(const short8*)&vin[o];
        float ps = 0.f;
#pragma unroll
        for (int i = 0; i < 8; ++i)
          ps += bf2f((unsigned short)val[i]) * bf2f((unsigned short)vv[i]);
        ps += __shfl_xor(ps, 1);
        ps += __shfl_xor(ps, 2);
        ps += __shfl_xor(ps, 4);
        ps += __shfl_xor(ps, 8);
        ps += __shfl_xor(ps, 16);
        if ((t & 31) == 0) atomicAdd(&inner[m0 + h * 128 + lr], ps);
      }
    }
    __syncthreads();
  }
}

__global__ void combine_ldj(const float* __restrict__ ldj_in, const float* __restrict__ inner,
                            float* __restrict__ out) {
  int b = blockIdx.x * 256 + threadIdx.x;
  if (b < BROWS) {
    float a = ldj_in[b];
#pragma unroll
    for (int k = 1; k <= NIT; k++) {
      float s = (k & 1) ? 1.f : -1.f;       // odd k: +, even k: -
      a += s * inner[(k - 1) * BROWS + b] / (float)k;
    }
    out[b] = a;
  }
}

extern "C" void kernel_launch(void* const* d_in, const int* in_sizes, int n_in,
                              void* d_out, int out_size, void* d_ws, size_t ws_size,
                              hipStream_t stream) {
  const float* y   = (const float*)d_in[0];
  const float* ldj = (const float*)d_in[1];
  const float* v   = (const float*)d_in[2];
  const float* W1  = (const float*)d_in[3];
  const float* b1  = (const float*)d_in[4];
  const float* W2  = (const float*)d_in[5];
  const float* b2  = (const float*)d_in[6];
  const float* W3  = (const float*)d_in[7];
  const float* b3  = (const float*)d_in[8];

  float* z_out   = (float*)d_out;                         // B*C fp32
  float* ldj_out = z_out + (size_t)BROWS * CDIM;          // B fp32

  const size_t MC = (size_t)BROWS * CDIM;                 // 16M elems
  const size_t WW = (size_t)3 * CDIM * CDIM;              // 3M elems
  unsigned short* Wb    = (unsigned short*)d_ws;          // 6 MB
  unsigned short* Wt    = Wb + WW;                        // 6 MB
  float*          inner = (float*)(Wt + WW);              // 1 MB
  unsigned short* ybf   = (unsigned short*)(inner + NIT * BROWS);
  unsigned short* ua    = ybf + MC;                       // 32 MB each (loop scratch)
  unsigned short* ub    = ua + MC;
  unsigned short* wv    = ub + MC;
  unsigned short* h1    = wv + MC;                        // persistent activations
  unsigned short* h2    = h1 + MC;

  prep_weights<<<(3 * CDIM * CDIM) / 256, 256, 0, stream>>>(W1, W2, W3, Wb, Wt);
  conv_inputs<<<(BROWS * CDIM) / (256 * 4), 256, 0, stream>>>(y, v, ybf, wv, inner);

  dim3 grid(256);  // 64 m-tiles x 4 n-tiles, 1 block/CU, XCD-swizzled in-kernel

  // forward: h1=elu(y@W1^T+b1), h2=elu(h1@W2^T+b2), z=y+h2@W3^T+b3
  gemm_k<0><<<grid, 512, 0, stream>>>(ybf, Wb,             b1, nullptr, nullptr, nullptr, h1, nullptr, nullptr);
  // ybf is free after GEMM1 -> reuse it for bf16(v)
  conv_v<<<(BROWS * CDIM) / (256 * 8), 256, 0, stream>>>(v, ybf);
  gemm_k<0><<<grid, 512, 0, stream>>>(h1,  Wb + (1 << 20), b2, nullptr, nullptr, nullptr, h2, nullptr, nullptr);
  gemm_k<1><<<grid, 512, 0, stream>>>(h2,  Wb + (2 << 20), b3, y,       nullptr, nullptr, nullptr, z_out, nullptr);

  // power series: w <- ((w@W3)*elu'(h2) @ W2)*elu'(h1) @ W1 ; inner_k = <w, v>
  for (int k = 1; k <= NIT; k++) {
    gemm_k<2><<<grid, 512, 0, stream>>>(wv, Wt + (2 << 20), nullptr, nullptr, h2, nullptr, ua, nullptr, nullptr);
    gemm_k<2><<<grid, 512, 0, stream>>>(ua, Wt + (1 << 20), nullptr, nullptr, h1, nullptr, ub, nullptr, nullptr);
    gemm_k<3><<<grid, 512, 0, stream>>>(ub, Wt,             nullptr, nullptr, nullptr, ybf, wv, nullptr, inner + (size_t)(k - 1) * BROWS);
  }

  combine_ldj<<<(BROWS + 255) / 256, 256, 0, stream>>>(ldj, inner, ldj_out);
}

// Round 5
// 2309.821 us; speedup vs baseline: 1.0360x; 1.0360x over previous
//
#include <hip/hip_runtime.h>
#include <cmath>

#define BROWS 16384
#define CDIM  1024
#define NIT   16

typedef __attribute__((ext_vector_type(8))) short short8;
typedef __attribute__((ext_vector_type(4))) short short4v;
typedef __attribute__((ext_vector_type(4))) float floatx4;

__device__ __forceinline__ unsigned short f2bf(float f) {
  union { float f; unsigned u; } x; x.f = f;
  unsigned r = x.u + 0x7fffu + ((x.u >> 16) & 1u);  // RNE
  return (unsigned short)(r >> 16);
}
__device__ __forceinline__ float bf2f(unsigned short h) {
  union { float f; unsigned u; } x; x.u = ((unsigned)h) << 16;
  return x.f;
}

// ---- one-time prep: weights fp32 -> bf16, both [n][k] and transposed ----
__global__ void prep_weights(const float* __restrict__ W1, const float* __restrict__ W2,
                             const float* __restrict__ W3,
                             unsigned short* __restrict__ Wb, unsigned short* __restrict__ Wt) {
  int idx = blockIdx.x * 256 + threadIdx.x;   // 0 .. 3*2^20-1
  int m = idx >> 20;
  int r = (idx >> 10) & 1023;
  int c = idx & 1023;
  const float* W = (m == 0) ? W1 : ((m == 1) ? W2 : W3);
  unsigned short b = f2bf(W[r * CDIM + c]);
  Wb[idx] = b;                                // forward: B[n][k] = W[n][k]
  Wt[(m << 20) + c * CDIM + r] = b;           // backward: B[n][k] = W[k][n]
}

__global__ void conv_inputs(const float* __restrict__ y, const float* __restrict__ v,
                            unsigned short* __restrict__ ybf, unsigned short* __restrict__ wbf,
                            float* __restrict__ inner) {
  int i = (blockIdx.x * 256 + threadIdx.x) * 4;   // vectorized x4
  floatx4 yv = *(const floatx4*)(y + i);
  floatx4 vv = *(const floatx4*)(v + i);
  short4v a, b;
#pragma unroll
  for (int r = 0; r < 4; r++) { a[r] = (short)f2bf(yv[r]); b[r] = (short)f2bf(vv[r]); }
  *(short4v*)(ybf + i) = a;
  *(short4v*)(wbf + i) = b;
  if (i < NIT * BROWS) *(floatx4*)(inner + i) = floatx4{0.f, 0.f, 0.f, 0.f};
}

// v fp32 -> bf16, into the (now free) ybf buffer; runs after GEMM1 on stream
__global__ void conv_v(const float* __restrict__ v, unsigned short* __restrict__ vb) {
  int i = (blockIdx.x * 256 + threadIdx.x) * 8;
  floatx4 a = *(const floatx4*)(v + i);
  floatx4 b = *(const floatx4*)(v + i + 4);
  short8 o;
#pragma unroll
  for (int r = 0; r < 4; r++) { o[r] = (short)f2bf(a[r]); o[r + 4] = (short)f2bf(b[r]); }
  *(short8*)(vb + i) = o;
}

// ---- GEMM: C[m,n] = sum_k A[m,k]*B[n,k]; A: M x K bf16, B: N x K bf16 ----
// 256x256 tile, BK=64, 512 threads (8 waves = 2M x 4N), 1 block/CU, grid=256.
// 4 phases/K-tile (R3 skeleton), work EVENED per phase:
//   reads: 12 pre-P0, bF1 under P0-MFMA, aF1(8) under P1-MFMA (WAR, HW interlock)
//   GLLs:  4 (A1+B2a) / 2 (B2b) / 2 (A2) / 0
//   waits: vmcnt(6)@P1-entry (retires cur A2, before hoisted aF1 reads),
//          vmcnt(2)@P3-end (A1/B2a/B2b aged >=2 phases; A2 flies on). 0 only at kt=15.
// MODE 0: FWD   outB = bf16(elu(acc+bias))          (activation only; no deriv buffer)
// MODE 1: FWD3  outZ = acc + bias + yin   (fp32)
// MODE 2: BWD   outB = bf16(acc * elu'(Dm)), elu'(h) = min(h+1, 1)  (Dm = activation)
// MODE 3: BWD3  outB = bf16(acc); inner[row] += sum_n acc*vin
template <int MODE>
__global__ __launch_bounds__(512, 2)
void gemm_k(const unsigned short* __restrict__ A,
            const unsigned short* __restrict__ Bm,
            const float* __restrict__ bias,
            const float* __restrict__ yin,
            const unsigned short* __restrict__ Dm,
            const unsigned short* __restrict__ vin,
            unsigned short* __restrict__ outB,
            float* __restrict__ outZ,
            float* __restrict__ inner) {
  constexpr int K = CDIM;
  // 128 KiB: 2 buffers x (A 256x64 + B 256x64) bf16, as 4 half-tiles of 128x64
  __shared__ unsigned short smem[65536];

  const int t = threadIdx.x;
  // 256 blocks = 64 m-tiles x 4 n-tiles; XCD swizzle: XCD x owns m-slab x (8 m-tiles),
  // and the 4 n-blocks of one m-tile land on the SAME XCD (A-panel L2 reuse).
  const int wg = (blockIdx.x & 7) * 32 + (blockIdx.x >> 3);
  const int m0 = (wg >> 2) * 256;
  const int n0 = (wg & 3) * 256;

  const int wave = t >> 6, lane = t & 63;
  const int quad = lane >> 4, ln = lane & 15;
  const int wm = wave >> 2;          // 0..1 : which 128-row half of the tile
  const int wn = wave & 3;           // 0..3 : which 64-col strip

  // staging: thread t loads 16B from global, LDS dest is lane-linear (t*16B);
  // the XOR swizzle lives in the GLOBAL column (global_load_lds can't scatter).
  const int srow = t >> 3;                              // 0..63
  const int gcolE = ((t & 7) ^ (srow & 7)) * 8;         // swizzled k-offset (elems)
  const unsigned short* gA = A + (size_t)(m0 + srow) * K + gcolE;
  const unsigned short* gB = Bm + (size_t)(n0 + srow) * K + gcolE;
  const int ldE = t * 8;                                // elems within half-tile

  // fragment-read swizzle (row&7 == ln&7 for all fragments)
  const int swzE = (ln & 7) << 3;
  const int aHalf = wm * 8192;                  // elems: A-top / A-bot
  const int bHalf = 16384 + (wn >> 1) * 8192;   // B-top / B-bot
  const int bRow = (wn & 1) * 64;               // 64-row slice within B half

#define GLL(gp, le)                                                                       \
  __builtin_amdgcn_global_load_lds((const __attribute__((address_space(1))) void*)(gp),   \
                                   (__attribute__((address_space(3))) void*)&smem[le], 16, 0, 0)
  // A-firsts: rows 0-63 of each 128-half (what aF0 reads need)
#define STAGE_A1(k0, pb) do {                                                             \
    GLL(gA + (k0),                    (pb) + ldE);                                        \
    GLL(gA + (size_t)128 * K + (k0),  (pb) + 8192 + ldE);                                 \
  } while (0)
  // A-seconds: rows 64-127 of each half (aF1 reads; issued LAST -> counted waits)
#define STAGE_A2(k0, pb) do {                                                             \
    GLL(gA + (size_t)64 * K + (k0),   (pb) + 4096 + ldE);                                 \
    GLL(gA + (size_t)192 * K + (k0),  (pb) + 8192 + 4096 + ldE);                          \
  } while (0)
#define STAGE_B2a(k0, pb) do {                                                            \
    GLL(gB + (k0),                    (pb) + 16384 + ldE);                                \
    GLL(gB + (size_t)64 * K + (k0),   (pb) + 16384 + 4096 + ldE);                         \
  } while (0)
#define STAGE_B2b(k0, pb) do {                                                            \
    GLL(gB + (size_t)128 * K + (k0),  (pb) + 16384 + 8192 + ldE);                         \
    GLL(gB + (size_t)192 * K + (k0),  (pb) + 16384 + 8192 + 4096 + ldE);                  \
  } while (0)

  floatx4 acc[8][4];
#pragma unroll
  for (int i = 0; i < 8; ++i)
#pragma unroll
    for (int j = 0; j < 4; ++j) acc[i][j] = {0.f, 0.f, 0.f, 0.f};

  short8 aF[4][2];   // current 64-row half of A fragments
  short8 bF[4][2];   // ALL B fragments for the wave's 64 cols (held whole K-tile)

  // prologue: stage buf0 in steady-state order; A-seconds may stay in flight
  STAGE_A1(0, 0); STAGE_B2a(0, 0); STAGE_B2b(0, 0); STAGE_A2(0, 0);
  asm volatile("s_waitcnt vmcnt(2)" ::: "memory");
  __builtin_amdgcn_s_barrier();

#define READ_A(qm_, bufE_) do {                                                           \
    _Pragma("unroll") for (int mi = 0; mi < 4; ++mi)                                      \
    _Pragma("unroll") for (int ks = 0; ks < 2; ++ks)                                      \
      aF[mi][ks] = *(const short8*)&smem[(bufE_) + aHalf + ((qm_) * 64 + mi * 16 + ln) * 64 \
                                         + ((ks * 32 + quad * 8) ^ swzE)];                \
  } while (0)
#define READ_B2(n0_, bufE_) do {                                                          \
    _Pragma("unroll") for (int ni = (n0_); ni < (n0_) + 2; ++ni)                          \
    _Pragma("unroll") for (int ks = 0; ks < 2; ++ks)                                      \
      bF[ni][ks] = *(const short8*)&smem[(bufE_) + bHalf + (bRow + ni * 16 + ln) * 64     \
                                         + ((ks * 32 + quad * 8) ^ swzE)];                \
  } while (0)
#define MFMA_Q(qm_, qn_) do {                                                             \
    _Pragma("unroll") for (int mi = 0; mi < 4; ++mi)                                      \
    _Pragma("unroll") for (int ni = 0; ni < 2; ++ni)                                      \
    _Pragma("unroll") for (int ks = 0; ks < 2; ++ks)                                      \
      acc[(qm_) * 4 + mi][(qn_) * 2 + ni] = __builtin_amdgcn_mfma_f32_16x16x32_bf16(      \
          aF[mi][ks], bF[(qn_) * 2 + ni][ks], acc[(qm_) * 4 + mi][(qn_) * 2 + ni], 0, 0, 0); \
  } while (0)

#pragma unroll 2
  for (int kt = 0; kt < 16; ++kt) {
    const int bufE = (kt & 1) * 32768;
    const int nxtE = bufE ^ 32768;
    const int kn = (kt + 1) * 64;
    const bool st = (kt < 15);

    // ---- P0: reads aF0+bF0 | stage next A-firsts + B-top ----
    READ_A(0, bufE);
    READ_B2(0, bufE);
    if (st) { STAGE_A1(kn, nxtE); STAGE_B2a(kn, nxtE); }
    __builtin_amdgcn_s_barrier();
    asm volatile("s_waitcnt lgkmcnt(0)" ::: "memory");
    __builtin_amdgcn_sched_barrier(0);
    __builtin_amdgcn_s_setprio(1);
    READ_B2(2, bufE);                 // bF1 issues under P0's MFMA (distinct regs)
    MFMA_Q(0, 0);
    __builtin_amdgcn_s_setprio(0);
    __builtin_amdgcn_sched_barrier(0);
    __builtin_amdgcn_s_barrier();

    // ---- P1: stage next B-bottom; counted vmcnt BEFORE aF1 hoist ----
    if (st) STAGE_B2b(kn, nxtE);
    __builtin_amdgcn_s_barrier();
    // retire cur-buf A-seconds (oldest 2) so the hoisted aF1 reads are safe;
    // next-buf loads (A1+B2a+B2b = 6) stay in flight
    if (kt == 15) asm volatile("s_waitcnt vmcnt(0)" ::: "memory");
    else          asm volatile("s_waitcnt vmcnt(6)" ::: "memory");
    asm volatile("s_waitcnt lgkmcnt(0)" ::: "memory");   // bF1
    __builtin_amdgcn_sched_barrier(0);
    __builtin_amdgcn_s_setprio(1);
    MFMA_Q(0, 1);
    READ_A(1, bufE);                  // aF1 issues under P1's MFMA (WAR, HW interlock)
    __builtin_amdgcn_s_setprio(0);
    __builtin_amdgcn_sched_barrier(0);
    __builtin_amdgcn_s_barrier();

    // ---- P2: stage next A-seconds (youngest loads) ----
    if (st) STAGE_A2(kn, nxtE);
    __builtin_amdgcn_s_barrier();
    asm volatile("s_waitcnt lgkmcnt(0)" ::: "memory");   // aF1
    __builtin_amdgcn_sched_barrier(0);
    __builtin_amdgcn_s_setprio(1);
    MFMA_Q(1, 0);
    __builtin_amdgcn_s_setprio(0);
    __builtin_amdgcn_sched_barrier(0);
    __builtin_amdgcn_s_barrier();

    // ---- P3: pure MFMA; counted drain of next A1+B (A2 flies on) ----
    __builtin_amdgcn_s_barrier();
    __builtin_amdgcn_s_setprio(1);
    MFMA_Q(1, 1);
    __builtin_amdgcn_s_setprio(0);
    __builtin_amdgcn_sched_barrier(0);
    if (st) asm volatile("s_waitcnt vmcnt(2)" ::: "memory");
    __builtin_amdgcn_s_barrier();
  }
#undef MFMA_Q
#undef READ_A
#undef READ_B2
#undef STAGE_A1
#undef STAGE_A2
#undef STAGE_B2a
#undef STAGE_B2b
#undef GLL

  // ---- epilogue: 2 rounds of 128 rows through LDS (stride 260: conflict-free
  // scalar writes, 8B-aligned reads), then coalesced global I/O ----
  unsigned short* Ct = smem;
  const int colW = wn * 64 + ln;
  float bv[4];
  if (MODE == 0) {
#pragma unroll
    for (int NI = 0; NI < 4; ++NI) bv[NI] = bias[n0 + colW + NI * 16];
  }
  for (int h = 0; h < 2; ++h) {
    if (wm == h) {
#pragma unroll
      for (int MI = 0; MI < 8; ++MI)
#pragma unroll
        for (int NI = 0; NI < 4; ++NI)
#pragma unroll
          for (int r = 0; r < 4; ++r) {
            float pv = acc[MI][NI][r];
            if (MODE == 0) {
              pv += bv[NI];
              pv = (pv > 0.f) ? pv : expm1f(pv);
            }
            Ct[(MI * 16 + quad * 4 + r) * 260 + colW + NI * 16] = f2bf(pv);
          }
    }
    __syncthreads();
    const int rr = t >> 5;            // 0..15
    const int cc = (t & 31) * 8;      // 0..248
#pragma unroll
    for (int it = 0; it < 8; ++it) {
      const int lr = it * 16 + rr;
      short4v v0 = *(const short4v*)&Ct[lr * 260 + cc];
      short4v v1 = *(const short4v*)&Ct[lr * 260 + cc + 4];
      short8 val;
#pragma unroll
      for (int i = 0; i < 4; ++i) { val[i] = v0[i]; val[i + 4] = v1[i]; }
      const size_t o = (size_t)(m0 + h * 128 + lr) * CDIM + (n0 + cc);
      if (MODE == 0) {
        *(short8*)&outB[o] = val;               // activation only; elu' derived by consumer
      } else if (MODE == 1) {
        const floatx4 y0 = *(const floatx4*)&yin[o];
        const floatx4 y1 = *(const floatx4*)&yin[o + 4];
        const floatx4 b0 = *(const floatx4*)&bias[n0 + cc];
        const floatx4 b1 = *(const floatx4*)&bias[n0 + cc + 4];
        floatx4 z0, z1;
#pragma unroll
        for (int i = 0; i < 4; ++i) {
          z0[i] = bf2f((unsigned short)val[i]) + b0[i] + y0[i];
          z1[i] = bf2f((unsigned short)val[i + 4]) + b1[i] + y1[i];
        }
        *(floatx4*)&outZ[o] = z0;
        *(floatx4*)&outZ[o + 4] = z1;
      } else if (MODE == 2) {
        short8 d = *(const short8*)&Dm[o];      // d = stored ACTIVATION h
        short8 ov;
#pragma unroll
        for (int i = 0; i < 8; ++i) {
          float dp = fminf(bf2f((unsigned short)d[i]) + 1.f, 1.f);  // elu'(h), branchless
          ov[i] = (short)f2bf(bf2f((unsigned short)val[i]) * dp);
        }
        *(short8*)&outB[o] = ov;
      } else {  // MODE 3
        *(short8*)&outB[o] = val;
        short8 vv = *(const short8*)&vin[o];
        float ps = 0.f;
#pragma unroll
        for (int i = 0; i < 8; ++i)
          ps += bf2f((unsigned short)val[i]) * bf2f((unsigned short)vv[i]);
        ps += __shfl_xor(ps, 1);
        ps += __shfl_xor(ps, 2);
        ps += __shfl_xor(ps, 4);
        ps += __shfl_xor(ps, 8);
        ps += __shfl_xor(ps, 16);
        if ((t & 31) == 0) atomicAdd(&inner[m0 + h * 128 + lr], ps);
      }
    }
    __syncthreads();
  }
}

__global__ void combine_ldj(const float* __restrict__ ldj_in, const float* __restrict__ inner,
                            float* __restrict__ out) {
  int b = blockIdx.x * 256 + threadIdx.x;
  if (b < BROWS) {
    float a = ldj_in[b];
#pragma unroll
    for (int k = 1; k <= NIT; k++) {
      float s = (k & 1) ? 1.f : -1.f;       // odd k: +, even k: -
      a += s * inner[(k - 1) * BROWS + b] / (float)k;
    }
    out[b] = a;
  }
}

extern "C" void kernel_launch(void* const* d_in, const int* in_sizes, int n_in,
                              void* d_out, int out_size, void* d_ws, size_t ws_size,
                              hipStream_t stream) {
  const float* y   = (const float*)d_in[0];
  const float* ldj = (const float*)d_in[1];
  const float* v   = (const float*)d_in[2];
  const float* W1  = (const float*)d_in[3];
  const float* b1  = (const float*)d_in[4];
  const float* W2  = (const float*)d_in[5];
  const float* b2  = (const float*)d_in[6];
  const float* W3  = (const float*)d_in[7];
  const float* b3  = (const float*)d_in[8];

  float* z_out   = (float*)d_out;                         // B*C fp32
  float* ldj_out = z_out + (size_t)BROWS * CDIM;          // B fp32

  const size_t MC = (size_t)BROWS * CDIM;                 // 16M elems
  const size_t WW = (size_t)3 * CDIM * CDIM;              // 3M elems
  unsigned short* Wb    = (unsigned short*)d_ws;          // 6 MB
  unsigned short* Wt    = Wb + WW;                        // 6 MB
  float*          inner = (float*)(Wt + WW);              // 1 MB
  unsigned short* ybf   = (unsigned short*)(inner + NIT * BROWS);
  unsigned short* ua    = ybf + MC;                       // 32 MB each (loop scratch)
  unsigned short* ub    = ua + MC;
  unsigned short* wv    = ub + MC;
  unsigned short* h1    = wv + MC;                        // persistent activations
  unsigned short* h2    = h1 + MC;

  prep_weights<<<(3 * CDIM * CDIM) / 256, 256, 0, stream>>>(W1, W2, W3, Wb, Wt);
  conv_inputs<<<(BROWS * CDIM) / (256 * 4), 256, 0, stream>>>(y, v, ybf, wv, inner);

  dim3 grid(256);  // 64 m-tiles x 4 n-tiles, 1 block/CU, XCD-swizzled in-kernel

  // forward: h1=elu(y@W1^T+b1), h2=elu(h1@W2^T+b2), z=y+h2@W3^T+b3
  gemm_k<0><<<grid, 512, 0, stream>>>(ybf, Wb,             b1, nullptr, nullptr, nullptr, h1, nullptr, nullptr);
  // ybf is free after GEMM1 -> reuse it for bf16(v)
  conv_v<<<(BROWS * CDIM) / (256 * 8), 256, 0, stream>>>(v, ybf);
  gemm_k<0><<<grid, 512, 0, stream>>>(h1,  Wb + (1 << 20), b2, nullptr, nullptr, nullptr, h2, nullptr, nullptr);
  gemm_k<1><<<grid, 512, 0, stream>>>(h2,  Wb + (2 << 20), b3, y,       nullptr, nullptr, nullptr, z_out, nullptr);

  // power series: w <- ((w@W3)*elu'(h2) @ W2)*elu'(h1) @ W1 ; inner_k = <w, v>
  for (int k = 1; k <= NIT; k++) {
    gemm_k<2><<<grid, 512, 0, stream>>>(wv, Wt + (2 << 20), nullptr, nullptr, h2, nullptr, ua, nullptr, nullptr);
    gemm_k<2><<<grid, 512, 0, stream>>>(ua, Wt + (1 << 20), nullptr, nullptr, h1, nullptr, ub, nullptr, nullptr);
    gemm_k<3><<<grid, 512, 0, stream>>>(ub, Wt,             nullptr, nullptr, nullptr, ybf, wv, nullptr, inner + (size_t)(k - 1) * BROWS);
  }

  combine_ldj<<<(BROWS + 255) / 256, 256, 0, stream>>>(ldj, inner, ldj_out);
}

// Round 6
// 1793.366 us; speedup vs baseline: 1.3344x; 1.2880x over previous
//
#include <hip/hip_runtime.h>
#include <cmath>

#define BROWS 16384
#define CDIM  1024
#define NIT   16

typedef __attribute__((ext_vector_type(8))) short short8;
typedef __attribute__((ext_vector_type(4))) short short4v;
typedef __attribute__((ext_vector_type(4))) float floatx4;

__device__ __forceinline__ unsigned short f2bf(float f) {
  union { float f; unsigned u; } x; x.f = f;
  unsigned r = x.u + 0x7fffu + ((x.u >> 16) & 1u);  // RNE
  return (unsigned short)(r >> 16);
}
__device__ __forceinline__ float bf2f(unsigned short h) {
  union { float f; unsigned u; } x; x.u = ((unsigned)h) << 16;
  return x.f;
}

// ---- one-time prep: weights fp32 -> bf16, both [n][k] and transposed ----
__global__ void prep_weights(const float* __restrict__ W1, const float* __restrict__ W2,
                             const float* __restrict__ W3,
                             unsigned short* __restrict__ Wb, unsigned short* __restrict__ Wt) {
  int idx = blockIdx.x * 256 + threadIdx.x;   // 0 .. 3*2^20-1
  int m = idx >> 20;
  int r = (idx >> 10) & 1023;
  int c = idx & 1023;
  const float* W = (m == 0) ? W1 : ((m == 1) ? W2 : W3);
  unsigned short b = f2bf(W[r * CDIM + c]);
  Wb[idx] = b;                                // forward: B[n][k] = W[n][k]
  Wt[(m << 20) + c * CDIM + r] = b;           // backward: B[n][k] = W[k][n]
}

__global__ void conv_inputs(const float* __restrict__ y, const float* __restrict__ v,
                            unsigned short* __restrict__ ybf, unsigned short* __restrict__ vbf,
                            float* __restrict__ inner) {
  int i = (blockIdx.x * 256 + threadIdx.x) * 4;   // vectorized x4
  floatx4 yv = *(const floatx4*)(y + i);
  floatx4 vv = *(const floatx4*)(v + i);
  short4v a, b;
#pragma unroll
  for (int r = 0; r < 4; r++) { a[r] = (short)f2bf(yv[r]); b[r] = (short)f2bf(vv[r]); }
  *(short4v*)(ybf + i) = a;
  *(short4v*)(vbf + i) = b;
  if (i < NIT * BROWS) *(floatx4*)(inner + i) = floatx4{0.f, 0.f, 0.f, 0.f};
}

// ---- GEMM: C[m,n] = sum_k A[m,k]*B[n,k]; A: M x K bf16, B: N x K bf16 ----
// 256x256 tile, BK=64, 512 threads (8 waves = 2M x 4N), 1 block/CU.
// Grid = 4*mtiles (linear tiles); 256-block grids get the XCD swizzle.
// R5's best-measured 4-phase K-loop schedule (counted vmcnt, evened phases).
// MODE 0: FWD   outB = bf16(elu(acc+bias))
// MODE 1: FWD3  outZ = acc + bias + yin   (fp32)
// MODE 2: BWD   outB = bf16(acc * elu'(Dm)),  elu'(h)=min(h+1,1)  (Dm = activation)
// MODE 3: BWD+DOT  outB as MODE 2; inner[row] += sum_n outB_unrounded * vin
// MODE 4: PLAIN outB = bf16(acc)            (q = v@W1 and M13 = combined matrix)
template <int MODE>
__global__ __launch_bounds__(512, 2)
void gemm_k(const unsigned short* __restrict__ A,
            const unsigned short* __restrict__ Bm,
            const float* __restrict__ bias,
            const float* __restrict__ yin,
            const unsigned short* __restrict__ Dm,
            const unsigned short* __restrict__ vin,
            unsigned short* __restrict__ outB,
            float* __restrict__ outZ,
            float* __restrict__ inner) {
  constexpr int K = CDIM;
  // 128 KiB: 2 buffers x (A 256x64 + B 256x64) bf16, as 4 half-tiles of 128x64
  __shared__ unsigned short smem[65536];

  const int t = threadIdx.x;
  // 256-block grids: XCD x owns m-slab x (A-panel L2 reuse). Small grids: linear.
  const int wg = (gridDim.x == 256) ? ((blockIdx.x & 7) * 32 + (blockIdx.x >> 3))
                                    : blockIdx.x;
  const int m0 = (wg >> 2) * 256;
  const int n0 = (wg & 3) * 256;

  const int wave = t >> 6, lane = t & 63;
  const int quad = lane >> 4, ln = lane & 15;
  const int wm = wave >> 2;          // 0..1 : which 128-row half of the tile
  const int wn = wave & 3;           // 0..3 : which 64-col strip

  // staging: thread t loads 16B from global, LDS dest is lane-linear (t*16B);
  // the XOR swizzle lives in the GLOBAL column (global_load_lds can't scatter).
  const int srow = t >> 3;                              // 0..63
  const int gcolE = ((t & 7) ^ (srow & 7)) * 8;         // swizzled k-offset (elems)
  const unsigned short* gA = A + (size_t)(m0 + srow) * K + gcolE;
  const unsigned short* gB = Bm + (size_t)(n0 + srow) * K + gcolE;
  const int ldE = t * 8;                                // elems within half-tile

  // fragment-read swizzle (row&7 == ln&7 for all fragments)
  const int swzE = (ln & 7) << 3;
  const int aHalf = wm * 8192;                  // elems: A-top / A-bot
  const int bHalf = 16384 + (wn >> 1) * 8192;   // B-top / B-bot
  const int bRow = (wn & 1) * 64;               // 64-row slice within B half

#define GLL(gp, le)                                                                       \
  __builtin_amdgcn_global_load_lds((const __attribute__((address_space(1))) void*)(gp),   \
                                   (__attribute__((address_space(3))) void*)&smem[le], 16, 0, 0)
#define STAGE_A1(k0, pb) do {                                                             \
    GLL(gA + (k0),                    (pb) + ldE);                                        \
    GLL(gA + (size_t)128 * K + (k0),  (pb) + 8192 + ldE);                                 \
  } while (0)
#define STAGE_A2(k0, pb) do {                                                             \
    GLL(gA + (size_t)64 * K + (k0),   (pb) + 4096 + ldE);                                 \
    GLL(gA + (size_t)192 * K + (k0),  (pb) + 8192 + 4096 + ldE);                          \
  } while (0)
#define STAGE_B2a(k0, pb) do {                                                            \
    GLL(gB + (k0),                    (pb) + 16384 + ldE);                                \
    GLL(gB + (size_t)64 * K + (k0),   (pb) + 16384 + 4096 + ldE);                         \
  } while (0)
#define STAGE_B2b(k0, pb) do {                                                            \
    GLL(gB + (size_t)128 * K + (k0),  (pb) + 16384 + 8192 + ldE);                         \
    GLL(gB + (size_t)192 * K + (k0),  (pb) + 16384 + 8192 + 4096 + ldE);                  \
  } while (0)

  floatx4 acc[8][4];
#pragma unroll
  for (int i = 0; i < 8; ++i)
#pragma unroll
    for (int j = 0; j < 4; ++j) acc[i][j] = {0.f, 0.f, 0.f, 0.f};

  short8 aF[4][2];   // current 64-row half of A fragments
  short8 bF[4][2];   // ALL B fragments for the wave's 64 cols (held whole K-tile)

  // prologue: stage buf0 in steady-state order; A-seconds may stay in flight
  STAGE_A1(0, 0); STAGE_B2a(0, 0); STAGE_B2b(0, 0); STAGE_A2(0, 0);
  asm volatile("s_waitcnt vmcnt(2)" ::: "memory");
  __builtin_amdgcn_s_barrier();

#define READ_A(qm_, bufE_) do {                                                           \
    _Pragma("unroll") for (int mi = 0; mi < 4; ++mi)                                      \
    _Pragma("unroll") for (int ks = 0; ks < 2; ++ks)                                      \
      aF[mi][ks] = *(const short8*)&smem[(bufE_) + aHalf + ((qm_) * 64 + mi * 16 + ln) * 64 \
                                         + ((ks * 32 + quad * 8) ^ swzE)];                \
  } while (0)
#define READ_B2(n0_, bufE_) do {                                                          \
    _Pragma("unroll") for (int ni = (n0_); ni < (n0_) + 2; ++ni)                          \
    _Pragma("unroll") for (int ks = 0; ks < 2; ++ks)                                      \
      bF[ni][ks] = *(const short8*)&smem[(bufE_) + bHalf + (bRow + ni * 16 + ln) * 64     \
                                         + ((ks * 32 + quad * 8) ^ swzE)];                \
  } while (0)
#define MFMA_Q(qm_, qn_) do {                                                             \
    _Pragma("unroll") for (int mi = 0; mi < 4; ++mi)                                      \
    _Pragma("unroll") for (int ni = 0; ni < 2; ++ni)                                      \
    _Pragma("unroll") for (int ks = 0; ks < 2; ++ks)                                      \
      acc[(qm_) * 4 + mi][(qn_) * 2 + ni] = __builtin_amdgcn_mfma_f32_16x16x32_bf16(      \
          aF[mi][ks], bF[(qn_) * 2 + ni][ks], acc[(qm_) * 4 + mi][(qn_) * 2 + ni], 0, 0, 0); \
  } while (0)

#pragma unroll 2
  for (int kt = 0; kt < 16; ++kt) {
    const int bufE = (kt & 1) * 32768;
    const int nxtE = bufE ^ 32768;
    const int kn = (kt + 1) * 64;
    const bool st = (kt < 15);

    // ---- P0: reads aF0+bF0 | stage next A-firsts + B-top ----
    READ_A(0, bufE);
    READ_B2(0, bufE);
    if (st) { STAGE_A1(kn, nxtE); STAGE_B2a(kn, nxtE); }
    __builtin_amdgcn_s_barrier();
    asm volatile("s_waitcnt lgkmcnt(0)" ::: "memory");
    __builtin_amdgcn_sched_barrier(0);
    __builtin_amdgcn_s_setprio(1);
    READ_B2(2, bufE);                 // bF1 issues under P0's MFMA (distinct regs)
    MFMA_Q(0, 0);
    __builtin_amdgcn_s_setprio(0);
    __builtin_amdgcn_sched_barrier(0);
    __builtin_amdgcn_s_barrier();

    // ---- P1: stage next B-bottom; counted vmcnt BEFORE aF1 hoist ----
    if (st) STAGE_B2b(kn, nxtE);
    __builtin_amdgcn_s_barrier();
    if (kt == 15) asm volatile("s_waitcnt vmcnt(0)" ::: "memory");
    else          asm volatile("s_waitcnt vmcnt(6)" ::: "memory");
    asm volatile("s_waitcnt lgkmcnt(0)" ::: "memory");   // bF1
    __builtin_amdgcn_sched_barrier(0);
    __builtin_amdgcn_s_setprio(1);
    MFMA_Q(0, 1);
    READ_A(1, bufE);                  // aF1 issues under P1's MFMA (WAR, HW interlock)
    __builtin_amdgcn_s_setprio(0);
    __builtin_amdgcn_sched_barrier(0);
    __builtin_amdgcn_s_barrier();

    // ---- P2: stage next A-seconds (youngest loads) ----
    if (st) STAGE_A2(kn, nxtE);
    __builtin_amdgcn_s_barrier();
    asm volatile("s_waitcnt lgkmcnt(0)" ::: "memory");   // aF1
    __builtin_amdgcn_sched_barrier(0);
    __builtin_amdgcn_s_setprio(1);
    MFMA_Q(1, 0);
    __builtin_amdgcn_s_setprio(0);
    __builtin_amdgcn_sched_barrier(0);
    __builtin_amdgcn_s_barrier();

    // ---- P3: pure MFMA; counted drain of next A1+B (A2 flies on) ----
    __builtin_amdgcn_s_barrier();
    __builtin_amdgcn_s_setprio(1);
    MFMA_Q(1, 1);
    __builtin_amdgcn_s_setprio(0);
    __builtin_amdgcn_sched_barrier(0);
    if (st) asm volatile("s_waitcnt vmcnt(2)" ::: "memory");
    __builtin_amdgcn_s_barrier();
  }
#undef MFMA_Q
#undef READ_A
#undef READ_B2
#undef STAGE_A1
#undef STAGE_A2
#undef STAGE_B2a
#undef STAGE_B2b
#undef GLL

  // ---- epilogue: 2 rounds of 128 rows through LDS (stride 260: conflict-free
  // scalar writes, 8B-aligned reads), then coalesced global I/O ----
  unsigned short* Ct = smem;
  const int colW = wn * 64 + ln;
  float bv[4];
  if (MODE == 0) {
#pragma unroll
    for (int NI = 0; NI < 4; ++NI) bv[NI] = bias[n0 + colW + NI * 16];
  }
  for (int h = 0; h < 2; ++h) {
    if (wm == h) {
#pragma unroll
      for (int MI = 0; MI < 8; ++MI)
#pragma unroll
        for (int NI = 0; NI < 4; ++NI)
#pragma unroll
          for (int r = 0; r < 4; ++r) {
            float pv = acc[MI][NI][r];
            if (MODE == 0) {
              pv += bv[NI];
              pv = (pv > 0.f) ? pv : expm1f(pv);
            }
            Ct[(MI * 16 + quad * 4 + r) * 260 + colW + NI * 16] = f2bf(pv);
          }
    }
    __syncthreads();
    const int rr = t >> 5;            // 0..15
    const int cc = (t & 31) * 8;      // 0..248
#pragma unroll
    for (int it = 0; it < 8; ++it) {
      const int lr = it * 16 + rr;
      short4v v0 = *(const short4v*)&Ct[lr * 260 + cc];
      short4v v1 = *(const short4v*)&Ct[lr * 260 + cc + 4];
      short8 val;
#pragma unroll
      for (int i = 0; i < 4; ++i) { val[i] = v0[i]; val[i + 4] = v1[i]; }
      const size_t o = (size_t)(m0 + h * 128 + lr) * CDIM + (n0 + cc);
      if (MODE == 0) {
        *(short8*)&outB[o] = val;               // activation only; elu' derived by consumer
      } else if (MODE == 1) {
        const floatx4 y0 = *(const floatx4*)&yin[o];
        const floatx4 y1 = *(const floatx4*)&yin[o + 4];
        const floatx4 b0 = *(const floatx4*)&bias[n0 + cc];
        const floatx4 b1 = *(const floatx4*)&bias[n0 + cc + 4];
        floatx4 z0, z1;
#pragma unroll
        for (int i = 0; i < 4; ++i) {
          z0[i] = bf2f((unsigned short)val[i]) + b0[i] + y0[i];
          z1[i] = bf2f((unsigned short)val[i + 4]) + b1[i] + y1[i];
        }
        *(floatx4*)&outZ[o] = z0;
        *(floatx4*)&outZ[o + 4] = z1;
      } else if (MODE == 2) {
        short8 d = *(const short8*)&Dm[o];      // d = stored ACTIVATION h
        short8 ov;
#pragma unroll
        for (int i = 0; i < 8; ++i) {
          float dp = fminf(bf2f((unsigned short)d[i]) + 1.f, 1.f);  // elu'(h)
          ov[i] = (short)f2bf(bf2f((unsigned short)val[i]) * dp);
        }
        *(short8*)&outB[o] = ov;
      } else if (MODE == 3) {                   // BWD + fused inner dot
        short8 d = *(const short8*)&Dm[o];
        short8 vv = *(const short8*)&vin[o];    // vin = q = v@W1
        short8 ov;
        float ps = 0.f;
#pragma unroll
        for (int i = 0; i < 8; ++i) {
          float dp = fminf(bf2f((unsigned short)d[i]) + 1.f, 1.f);
          float pu = bf2f((unsigned short)val[i]) * dp;
          ov[i] = (short)f2bf(pu);
          ps += pu * bf2f((unsigned short)vv[i]);
        }
        *(short8*)&outB[o] = ov;
        ps += __shfl_xor(ps, 1);
        ps += __shfl_xor(ps, 2);
        ps += __shfl_xor(ps, 4);
        ps += __shfl_xor(ps, 8);
        ps += __shfl_xor(ps, 16);
        if ((t & 31) == 0) atomicAdd(&inner[m0 + h * 128 + lr], ps);
      } else {  // MODE 4: plain bf16 store
        *(short8*)&outB[o] = val;
      }
    }
    __syncthreads();
  }
}

__global__ void combine_ldj(const float* __restrict__ ldj_in, const float* __restrict__ inner,
                            float* __restrict__ out) {
  int b = blockIdx.x * 256 + threadIdx.x;
  if (b < BROWS) {
    float a = ldj_in[b];
#pragma unroll
    for (int k = 1; k <= NIT; k++) {
      float s = (k & 1) ? 1.f : -1.f;       // odd k: +, even k: -
      a += s * inner[(k - 1) * BROWS + b] / (float)k;
    }
    out[b] = a;
  }
}

extern "C" void kernel_launch(void* const* d_in, const int* in_sizes, int n_in,
                              void* d_out, int out_size, void* d_ws, size_t ws_size,
                              hipStream_t stream) {
  const float* y   = (const float*)d_in[0];
  const float* ldj = (const float*)d_in[1];
  const float* v   = (const float*)d_in[2];
  const float* W1  = (const float*)d_in[3];
  const float* b1  = (const float*)d_in[4];
  const float* W2  = (const float*)d_in[5];
  const float* b2  = (const float*)d_in[6];
  const float* W3  = (const float*)d_in[7];
  const float* b3  = (const float*)d_in[8];

  float* z_out   = (float*)d_out;                         // B*C fp32
  float* ldj_out = z_out + (size_t)BROWS * CDIM;          // B fp32

  const size_t MC = (size_t)BROWS * CDIM;                 // 16M elems
  const size_t WW = (size_t)3 * CDIM * CDIM;              // 3M elems
  unsigned short* Wb    = (unsigned short*)d_ws;          // 6 MB
  unsigned short* Wt    = Wb + WW;                        // 6 MB
  float*          inner = (float*)(Wt + WW);              // 1 MB
  unsigned short* ybf   = (unsigned short*)(inner + NIT * BROWS);  // y, then reused as q
  unsigned short* ua    = ybf + MC;                       // 32 MB each
  unsigned short* ub    = ua + MC;
  unsigned short* vb    = ub + MC;                        // bf16(v)
  unsigned short* h1    = vb + MC;                        // persistent activations
  unsigned short* h2    = h1 + MC;
  unsigned short* M13   = h2 + MC;                        // 2 MB: combined W1*W3 (B-stored)

  prep_weights<<<(3 * CDIM * CDIM) / 256, 256, 0, stream>>>(W1, W2, W3, Wb, Wt);
  conv_inputs<<<(BROWS * CDIM) / (256 * 4), 256, 0, stream>>>(y, v, ybf, vb, inner);

  dim3 grid(256);   // 64 m-tiles x 4 n-tiles
  dim3 gridW(16);   // 4 m-tiles x 4 n-tiles (1024-row GEMM)

  // M13[j,k] = sum_n Wt3[j,n]*Wb1[k,n] = sum_n W3[n,j]*W1[k,n]  -> (ub@W1)@W3 == ub@M13
  gemm_k<4><<<gridW, 512, 0, stream>>>(Wt + (2 << 20), Wb, nullptr, nullptr, nullptr, nullptr, M13, nullptr, nullptr);

  // forward: h1=elu(y@W1^T+b1), h2=elu(h1@W2^T+b2), z=y+h2@W3^T+b3
  gemm_k<0><<<grid, 512, 0, stream>>>(ybf, Wb,             b1, nullptr, nullptr, nullptr, h1, nullptr, nullptr);
  // ybf free now -> q = v@W1 (q[b,k] = sum_n v[b,n]*W1[k,n]; B = Wb1)
  gemm_k<4><<<grid, 512, 0, stream>>>(vb,  Wb,             nullptr, nullptr, nullptr, nullptr, ybf, nullptr, nullptr);
  gemm_k<0><<<grid, 512, 0, stream>>>(h1,  Wb + (1 << 20), b2, nullptr, nullptr, nullptr, h2, nullptr, nullptr);
  gemm_k<1><<<grid, 512, 0, stream>>>(h2,  Wb + (2 << 20), b3, y,       nullptr, nullptr, nullptr, z_out, nullptr);

  // power series with collapsed W1*W3:
  //   ua_1 = (v@W3)∘d2 ; for k: ub_k = (ua_k@W2)∘d1, inner_k = <ub_k, q>;
  //   ua_{k+1} = (ub_k@M13)∘d2
  gemm_k<2><<<grid, 512, 0, stream>>>(vb, Wt + (2 << 20), nullptr, nullptr, h2, nullptr, ua, nullptr, nullptr);
  for (int k = 1; k <= NIT; k++) {
    gemm_k<3><<<grid, 512, 0, stream>>>(ua, Wt + (1 << 20), nullptr, nullptr, h1, ybf, ub, nullptr, inner + (size_t)(k - 1) * BROWS);
    if (k < NIT)
      gemm_k<2><<<grid, 512, 0, stream>>>(ub, M13, nullptr, nullptr, h2, nullptr, ua, nullptr, nullptr);
  }

  combine_ldj<<<(BROWS + 255) / 256, 256, 0, stream>>>(ldj, inner, ldj_out);
}

// Round 7
// 1724.507 us; speedup vs baseline: 1.3877x; 1.0399x over previous
//
#include <hip/hip_runtime.h>
#include <cmath>

#define BROWS 16384
#define CDIM  1024
#define NIT   16

typedef __attribute__((ext_vector_type(8))) short short8;
typedef __attribute__((ext_vector_type(4))) short short4v;
typedef __attribute__((ext_vector_type(4))) float floatx4;

__device__ __forceinline__ unsigned short f2bf(float f) {
  union { float f; unsigned u; } x; x.f = f;
  unsigned r = x.u + 0x7fffu + ((x.u >> 16) & 1u);  // RNE
  return (unsigned short)(r >> 16);
}
__device__ __forceinline__ float bf2f(unsigned short h) {
  union { float f; unsigned u; } x; x.u = ((unsigned)h) << 16;
  return x.f;
}

// ---- one-time prep: weights fp32 -> bf16, both [n][k] and transposed ----
__global__ void prep_weights(const float* __restrict__ W1, const float* __restrict__ W2,
                             const float* __restrict__ W3,
                             unsigned short* __restrict__ Wb, unsigned short* __restrict__ Wt) {
  int idx = blockIdx.x * 256 + threadIdx.x;   // 0 .. 3*2^20-1
  int m = idx >> 20;
  int r = (idx >> 10) & 1023;
  int c = idx & 1023;
  const float* W = (m == 0) ? W1 : ((m == 1) ? W2 : W3);
  unsigned short b = f2bf(W[r * CDIM + c]);
  Wb[idx] = b;                                // forward: B[n][k] = W[n][k]
  Wt[(m << 20) + c * CDIM + r] = b;           // backward: B[n][k] = W[k][n]
}

__global__ void conv_inputs(const float* __restrict__ y, const float* __restrict__ v,
                            unsigned short* __restrict__ ybf, unsigned short* __restrict__ vbf,
                            float* __restrict__ inner) {
  int i = (blockIdx.x * 256 + threadIdx.x) * 4;   // vectorized x4
  floatx4 yv = *(const floatx4*)(y + i);
  floatx4 vv = *(const floatx4*)(v + i);
  short4v a, b;
#pragma unroll
  for (int r = 0; r < 4; r++) { a[r] = (short)f2bf(yv[r]); b[r] = (short)f2bf(vv[r]); }
  *(short4v*)(ybf + i) = a;
  *(short4v*)(vbf + i) = b;
  if (i < NIT * BROWS) *(floatx4*)(inner + i) = floatx4{0.f, 0.f, 0.f, 0.f};
}

// ---- small 1024^3 GEMM (M13 = Wt3 x Wb1): 128^2 tiles, grid 64, 4 waves ----
// Same C[m,n] = sum_k A[m,k]*B[n,k] convention and same stage/read swizzle
// identity as gemm_k. m97-style syncthreads pipeline (compiler-inserted waits).
__global__ __launch_bounds__(256, 2)
void gemm_w(const unsigned short* __restrict__ A, const unsigned short* __restrict__ Bm,
            unsigned short* __restrict__ outB) {
  constexpr int K = CDIM;
  __shared__ unsigned short smem[32768];      // 64 KiB: 2 buf x (A 128x64 + B 128x64)
  const int t = threadIdx.x;
  const int m0 = (blockIdx.x >> 3) * 128;     // 8 x 8 tiles
  const int n0 = (blockIdx.x & 7) * 128;
  const int wave = t >> 6, lane = t & 63;
  const int quad = lane >> 4, ln = lane & 15;
  const int wm = wave >> 1, wn = wave & 1;    // 2x2 waves, 64x64 each
  const int srow = t >> 3;                    // 0..31
  const int gcolE = ((t & 7) ^ (srow & 7)) * 8;
  const unsigned short* gA = A + (size_t)(m0 + srow) * K + gcolE;
  const unsigned short* gB = Bm + (size_t)(n0 + srow) * K + gcolE;
  const int ldE = t * 8;
  const int swzE = (ln & 7) << 3;

#define GLLW(gp, le)                                                                      \
  __builtin_amdgcn_global_load_lds((const __attribute__((address_space(1))) void*)(gp),   \
                                   (__attribute__((address_space(3))) void*)&smem[le], 16, 0, 0)
#define STAGEW(k0, pb) do {                                                               \
    _Pragma("unroll") for (int g = 0; g < 4; ++g) {                                       \
      GLLW(gA + (size_t)(g * 32) * K + (k0), (pb) + g * 2048 + ldE);                      \
      GLLW(gB + (size_t)(g * 32) * K + (k0), (pb) + 8192 + g * 2048 + ldE);               \
    }                                                                                     \
  } while (0)

  floatx4 acc[4][4];
#pragma unroll
  for (int i = 0; i < 4; ++i)
#pragma unroll
    for (int j = 0; j < 4; ++j) acc[i][j] = {0.f, 0.f, 0.f, 0.f};

  STAGEW(0, 0);
  for (int kt = 0; kt < 16; ++kt) {
    const int cb = (kt & 1) * 16384;
    __syncthreads();                          // drains current tile's GLLs
    if (kt < 15) STAGEW((kt + 1) * 64, cb ^ 16384);
    short8 aF[4][2], bF[4][2];
#pragma unroll
    for (int mi = 0; mi < 4; ++mi)
#pragma unroll
      for (int ks = 0; ks < 2; ++ks)
        aF[mi][ks] = *(const short8*)&smem[cb + (wm * 64 + mi * 16 + ln) * 64
                                           + ((ks * 32 + quad * 8) ^ swzE)];
#pragma unroll
    for (int ni = 0; ni < 4; ++ni)
#pragma unroll
      for (int ks = 0; ks < 2; ++ks)
        bF[ni][ks] = *(const short8*)&smem[cb + 8192 + (wn * 64 + ni * 16 + ln) * 64
                                           + ((ks * 32 + quad * 8) ^ swzE)];
#pragma unroll
    for (int mi = 0; mi < 4; ++mi)
#pragma unroll
      for (int ni = 0; ni < 4; ++ni)
#pragma unroll
        for (int ks = 0; ks < 2; ++ks)
          acc[mi][ni] = __builtin_amdgcn_mfma_f32_16x16x32_bf16(aF[mi][ks], bF[ni][ks],
                                                                acc[mi][ni], 0, 0, 0);
  }
  __syncthreads();

  unsigned short* Ct = smem;                  // 128 x 132 (33792 B < 64 KiB)
#pragma unroll
  for (int mi = 0; mi < 4; ++mi)
#pragma unroll
    for (int ni = 0; ni < 4; ++ni)
#pragma unroll
      for (int r = 0; r < 4; ++r)
        Ct[(wm * 64 + mi * 16 + quad * 4 + r) * 132 + wn * 64 + ln + ni * 16] =
            f2bf(acc[mi][ni][r]);
  __syncthreads();
  const int rr = t >> 4, cc = (t & 15) * 8;
#pragma unroll
  for (int it = 0; it < 8; ++it) {
    const int lr = it * 16 + rr;
    short4v v0 = *(const short4v*)&Ct[lr * 132 + cc];
    short4v v1 = *(const short4v*)&Ct[lr * 132 + cc + 4];
    short8 val;
#pragma unroll
    for (int i = 0; i < 4; ++i) { val[i] = v0[i]; val[i + 4] = v1[i]; }
    *(short8*)&outB[(size_t)(m0 + lr) * CDIM + (n0 + cc)] = val;
  }
#undef STAGEW
#undef GLLW
}

// ---- GEMM: C[m,n] = sum_k A[m,k]*B[n,k]; A: M x K bf16, B: N x K bf16 ----
// 256x256 tile, BK=64, 512 threads (8 waves = 2M x 4N), 1 block/CU, grid 256.
// 4-phase K-loop, counted vmcnt asm only; LDS waits left to the compiler's
// precise per-use lgkmcnt (all ds_reads are plain loads).
// MODE 0: FWD   outB = bf16(elu(acc+bias))
// MODE 1: FWD3  outZ = acc + bias + yin   (fp32)
// MODE 2: BWD   outB = bf16(acc * elu'(Dm)),  elu'(h)=min(h+1,1)  (Dm = activation)
// MODE 3: BWD+DOT  outB as MODE 2; inner[row] += sum_n unrounded * vin
// MODE 4: PLAIN outB = bf16(acc)
// MODE 5: DOT-ONLY (MODE 3 without the outB store; k=NIT's ub is never read)
template <int MODE>
__global__ __launch_bounds__(512, 2)
void gemm_k(const unsigned short* __restrict__ A,
            const unsigned short* __restrict__ Bm,
            const float* __restrict__ bias,
            const float* __restrict__ yin,
            const unsigned short* __restrict__ Dm,
            const unsigned short* __restrict__ vin,
            unsigned short* __restrict__ outB,
            float* __restrict__ outZ,
            float* __restrict__ inner) {
  constexpr int K = CDIM;
  __shared__ unsigned short smem[65536];

  const int t = threadIdx.x;
  const int wg = (blockIdx.x & 7) * 32 + (blockIdx.x >> 3);  // XCD swizzle
  const int m0 = (wg >> 2) * 256;
  const int n0 = (wg & 3) * 256;

  const int wave = t >> 6, lane = t & 63;
  const int quad = lane >> 4, ln = lane & 15;
  const int wm = wave >> 2;
  const int wn = wave & 3;

  const int srow = t >> 3;
  const int gcolE = ((t & 7) ^ (srow & 7)) * 8;
  const unsigned short* gA = A + (size_t)(m0 + srow) * K + gcolE;
  const unsigned short* gB = Bm + (size_t)(n0 + srow) * K + gcolE;
  const int ldE = t * 8;

  const int swzE = (ln & 7) << 3;
  const int aHalf = wm * 8192;
  const int bHalf = 16384 + (wn >> 1) * 8192;
  const int bRow = (wn & 1) * 64;

#define GLL(gp, le)                                                                       \
  __builtin_amdgcn_global_load_lds((const __attribute__((address_space(1))) void*)(gp),   \
                                   (__attribute__((address_space(3))) void*)&smem[le], 16, 0, 0)
#define STAGE_A1(k0, pb) do {                                                             \
    GLL(gA + (k0),                    (pb) + ldE);                                        \
    GLL(gA + (size_t)128 * K + (k0),  (pb) + 8192 + ldE);                                 \
  } while (0)
#define STAGE_A2(k0, pb) do {                                                             \
    GLL(gA + (size_t)64 * K + (k0),   (pb) + 4096 + ldE);                                 \
    GLL(gA + (size_t)192 * K + (k0),  (pb) + 8192 + 4096 + ldE);                          \
  } while (0)
#define STAGE_B2a(k0, pb) do {                                                            \
    GLL(gB + (k0),                    (pb) + 16384 + ldE);                                \
    GLL(gB + (size_t)64 * K + (k0),   (pb) + 16384 + 4096 + ldE);                         \
  } while (0)
#define STAGE_B2b(k0, pb) do {                                                            \
    GLL(gB + (size_t)128 * K + (k0),  (pb) + 16384 + 8192 + ldE);                         \
    GLL(gB + (size_t)192 * K + (k0),  (pb) + 16384 + 8192 + 4096 + ldE);                  \
  } while (0)

  floatx4 acc[8][4];
#pragma unroll
  for (int i = 0; i < 8; ++i)
#pragma unroll
    for (int j = 0; j < 4; ++j) acc[i][j] = {0.f, 0.f, 0.f, 0.f};

  short8 aF[4][2];
  short8 bF[4][2];

  STAGE_A1(0, 0); STAGE_B2a(0, 0); STAGE_B2b(0, 0); STAGE_A2(0, 0);
  asm volatile("s_waitcnt vmcnt(2)" ::: "memory");
  __builtin_amdgcn_s_barrier();

#define READ_A(qm_, bufE_) do {                                                           \
    _Pragma("unroll") for (int mi = 0; mi < 4; ++mi)                                      \
    _Pragma("unroll") for (int ks = 0; ks < 2; ++ks)                                      \
      aF[mi][ks] = *(const short8*)&smem[(bufE_) + aHalf + ((qm_) * 64 + mi * 16 + ln) * 64 \
                                         + ((ks * 32 + quad * 8) ^ swzE)];                \
  } while (0)
#define READ_B2(n0_, bufE_) do {                                                          \
    _Pragma("unroll") for (int ni = (n0_); ni < (n0_) + 2; ++ni)                          \
    _Pragma("unroll") for (int ks = 0; ks < 2; ++ks)                                      \
      bF[ni][ks] = *(const short8*)&smem[(bufE_) + bHalf + (bRow + ni * 16 + ln) * 64     \
                                         + ((ks * 32 + quad * 8) ^ swzE)];                \
  } while (0)
#define MFMA_Q(qm_, qn_) do {                                                             \
    _Pragma("unroll") for (int mi = 0; mi < 4; ++mi)                                      \
    _Pragma("unroll") for (int ni = 0; ni < 2; ++ni)                                      \
    _Pragma("unroll") for (int ks = 0; ks < 2; ++ks)                                      \
      acc[(qm_) * 4 + mi][(qn_) * 2 + ni] = __builtin_amdgcn_mfma_f32_16x16x32_bf16(      \
          aF[mi][ks], bF[(qn_) * 2 + ni][ks], acc[(qm_) * 4 + mi][(qn_) * 2 + ni], 0, 0, 0); \
  } while (0)

#pragma unroll 2
  for (int kt = 0; kt < 16; ++kt) {
    const int bufE = (kt & 1) * 32768;
    const int nxtE = bufE ^ 32768;
    const int kn = (kt + 1) * 64;
    const bool st = (kt < 15);

    // ---- P0: reads aF0+bF0 | stage next A-firsts + B-top ----
    READ_A(0, bufE);
    READ_B2(0, bufE);
    if (st) { STAGE_A1(kn, nxtE); STAGE_B2a(kn, nxtE); }
    __builtin_amdgcn_s_barrier();
    __builtin_amdgcn_sched_barrier(0);
    __builtin_amdgcn_s_setprio(1);
    READ_B2(2, bufE);                 // bF1 issues under P0's MFMA
    MFMA_Q(0, 0);                     // compiler emits precise lgkmcnt for aF0/bF0
    __builtin_amdgcn_s_setprio(0);
    __builtin_amdgcn_sched_barrier(0);
    __builtin_amdgcn_s_barrier();

    // ---- P1: stage next B-bottom; counted vmcnt BEFORE aF1 hoist ----
    if (st) STAGE_B2b(kn, nxtE);
    __builtin_amdgcn_s_barrier();
    if (kt == 15) asm volatile("s_waitcnt vmcnt(0)" ::: "memory");
    else          asm volatile("s_waitcnt vmcnt(6)" ::: "memory");  // retires cur A2
    __builtin_amdgcn_sched_barrier(0);
    __builtin_amdgcn_s_setprio(1);
    MFMA_Q(0, 1);                     // compiler waits bF1 precisely
    READ_A(1, bufE);                  // aF1 under P1's MFMA (WAR, HW interlock)
    __builtin_amdgcn_s_setprio(0);
    __builtin_amdgcn_sched_barrier(0);
    __builtin_amdgcn_s_barrier();

    // ---- P2: stage next A-seconds (youngest loads) ----
    if (st) STAGE_A2(kn, nxtE);
    __builtin_amdgcn_s_barrier();
    __builtin_amdgcn_sched_barrier(0);
    __builtin_amdgcn_s_setprio(1);
    MFMA_Q(1, 0);                     // compiler waits aF1 precisely
    __builtin_amdgcn_s_setprio(0);
    __builtin_amdgcn_sched_barrier(0);
    __builtin_amdgcn_s_barrier();

    // ---- P3: pure MFMA; counted drain of next A1+B (A2 flies on) ----
    __builtin_amdgcn_s_barrier();
    __builtin_amdgcn_s_setprio(1);
    MFMA_Q(1, 1);
    __builtin_amdgcn_s_setprio(0);
    __builtin_amdgcn_sched_barrier(0);
    if (st) asm volatile("s_waitcnt vmcnt(2)" ::: "memory");
    __builtin_amdgcn_s_barrier();
  }
#undef MFMA_Q
#undef READ_A
#undef READ_B2
#undef STAGE_A1
#undef STAGE_A2
#undef STAGE_B2a
#undef STAGE_B2b
#undef GLL

  // ---- epilogue: 2 rounds of 128 rows through LDS (stride 260) ----
  unsigned short* Ct = smem;
  const int colW = wn * 64 + ln;
  float bv[4];
  if (MODE == 0) {
#pragma unroll
    for (int NI = 0; NI < 4; ++NI) bv[NI] = bias[n0 + colW + NI * 16];
  }
  for (int h = 0; h < 2; ++h) {
    if (wm == h) {
#pragma unroll
      for (int MI = 0; MI < 8; ++MI)
#pragma unroll
        for (int NI = 0; NI < 4; ++NI)
#pragma unroll
          for (int r = 0; r < 4; ++r) {
            float pv = acc[MI][NI][r];
            if (MODE == 0) {
              pv += bv[NI];
              pv = (pv > 0.f) ? pv : expm1f(pv);
            }
            Ct[(MI * 16 + quad * 4 + r) * 260 + colW + NI * 16] = f2bf(pv);
          }
    }
    __syncthreads();
    const int rr = t >> 5;            // 0..15
    const int cc = (t & 31) * 8;      // 0..248
#pragma unroll
    for (int it = 0; it < 8; ++it) {
      const int lr = it * 16 + rr;
      short4v v0 = *(const short4v*)&Ct[lr * 260 + cc];
      short4v v1 = *(const short4v*)&Ct[lr * 260 + cc + 4];
      short8 val;
#pragma unroll
      for (int i = 0; i < 4; ++i) { val[i] = v0[i]; val[i + 4] = v1[i]; }
      const size_t o = (size_t)(m0 + h * 128 + lr) * CDIM + (n0 + cc);
      if (MODE == 0) {
        *(short8*)&outB[o] = val;               // activation only
      } else if (MODE == 1) {
        const floatx4 y0 = *(const floatx4*)&yin[o];
        const floatx4 y1 = *(const floatx4*)&yin[o + 4];
        const floatx4 b0 = *(const floatx4*)&bias[n0 + cc];
        const floatx4 b1 = *(const floatx4*)&bias[n0 + cc + 4];
        floatx4 z0, z1;
#pragma unroll
        for (int i = 0; i < 4; ++i) {
          z0[i] = bf2f((unsigned short)val[i]) + b0[i] + y0[i];
          z1[i] = bf2f((unsigned short)val[i + 4]) + b1[i] + y1[i];
        }
        *(floatx4*)&outZ[o] = z0;
        *(floatx4*)&outZ[o + 4] = z1;
      } else if (MODE == 2) {
        short8 d = *(const short8*)&Dm[o];
        short8 ov;
#pragma unroll
        for (int i = 0; i < 8; ++i) {
          float dp = fminf(bf2f((unsigned short)d[i]) + 1.f, 1.f);
          ov[i] = (short)f2bf(bf2f((unsigned short)val[i]) * dp);
        }
        *(short8*)&outB[o] = ov;
      } else if (MODE == 3 || MODE == 5) {      // BWD + fused inner dot
        short8 d = *(const short8*)&Dm[o];
        short8 vv = *(const short8*)&vin[o];
        short8 ov;
        float ps = 0.f;
#pragma unroll
        for (int i = 0; i < 8; ++i) {
          float dp = fminf(bf2f((unsigned short)d[i]) + 1.f, 1.f);
          float pu = bf2f((unsigned short)val[i]) * dp;
          ov[i] = (short)f2bf(pu);
          ps += pu * bf2f((unsigned short)vv[i]);
        }
        if (MODE == 3) *(short8*)&outB[o] = ov;
        ps += __shfl_xor(ps, 1);
        ps += __shfl_xor(ps, 2);
        ps += __shfl_xor(ps, 4);
        ps += __shfl_xor(ps, 8);
        ps += __shfl_xor(ps, 16);
        if ((t & 31) == 0) atomicAdd(&inner[m0 + h * 128 + lr], ps);
      } else {  // MODE 4
        *(short8*)&outB[o] = val;
      }
    }
    __syncthreads();
  }
}

__global__ void combine_ldj(const float* __restrict__ ldj_in, const float* __restrict__ inner,
                            float* __restrict__ out) {
  int b = blockIdx.x * 256 + threadIdx.x;
  if (b < BROWS) {
    float a = ldj_in[b];
#pragma unroll
    for (int k = 1; k <= NIT; k++) {
      float s = (k & 1) ? 1.f : -1.f;
      a += s * inner[(k - 1) * BROWS + b] / (float)k;
    }
    out[b] = a;
  }
}

extern "C" void kernel_launch(void* const* d_in, const int* in_sizes, int n_in,
                              void* d_out, int out_size, void* d_ws, size_t ws_size,
                              hipStream_t stream) {
  const float* y   = (const float*)d_in[0];
  const float* ldj = (const float*)d_in[1];
  const float* v   = (const float*)d_in[2];
  const float* W1  = (const float*)d_in[3];
  const float* b1  = (const float*)d_in[4];
  const float* W2  = (const float*)d_in[5];
  const float* b2  = (const float*)d_in[6];
  const float* W3  = (const float*)d_in[7];
  const float* b3  = (const float*)d_in[8];

  float* z_out   = (float*)d_out;                         // B*C fp32
  float* ldj_out = z_out + (size_t)BROWS * CDIM;          // B fp32

  const size_t MC = (size_t)BROWS * CDIM;                 // 16M elems
  const size_t WW = (size_t)3 * CDIM * CDIM;              // 3M elems
  unsigned short* Wb    = (unsigned short*)d_ws;          // 6 MB
  unsigned short* Wt    = Wb + WW;                        // 6 MB
  float*          inner = (float*)(Wt + WW);              // 1 MB
  unsigned short* ybf   = (unsigned short*)(inner + NIT * BROWS);  // y, then reused as q
  unsigned short* ua    = ybf + MC;                       // 32 MB each
  unsigned short* ub    = ua + MC;
  unsigned short* vb    = ub + MC;                        // bf16(v)
  unsigned short* h1    = vb + MC;                        // persistent activations
  unsigned short* h2    = h1 + MC;
  unsigned short* M13   = h2 + MC;                        // 2 MB: combined W1*W3

  prep_weights<<<(3 * CDIM * CDIM) / 256, 256, 0, stream>>>(W1, W2, W3, Wb, Wt);
  conv_inputs<<<(BROWS * CDIM) / (256 * 4), 256, 0, stream>>>(y, v, ybf, vb, inner);

  dim3 grid(256);   // 64 m-tiles x 4 n-tiles

  // M13[j,k] = sum_n Wt3[j,n]*Wb1[k,n]  ->  (ub@W1)@W3 == ub@M13. grid 64 mini-GEMM.
  gemm_w<<<64, 256, 0, stream>>>(Wt + (2 << 20), Wb, M13);

  // forward: h1=elu(y@W1^T+b1), h2=elu(h1@W2^T+b2), z=y+h2@W3^T+b3
  gemm_k<0><<<grid, 512, 0, stream>>>(ybf, Wb,             b1, nullptr, nullptr, nullptr, h1, nullptr, nullptr);
  // ybf free now -> q = v@W1
  gemm_k<4><<<grid, 512, 0, stream>>>(vb,  Wb,             nullptr, nullptr, nullptr, nullptr, ybf, nullptr, nullptr);
  gemm_k<0><<<grid, 512, 0, stream>>>(h1,  Wb + (1 << 20), b2, nullptr, nullptr, nullptr, h2, nullptr, nullptr);
  gemm_k<1><<<grid, 512, 0, stream>>>(h2,  Wb + (2 << 20), b3, y,       nullptr, nullptr, nullptr, z_out, nullptr);

  // power series with collapsed W1*W3:
  //   ua_1 = (v@W3)∘d2 ; for k: ub_k = (ua_k@W2)∘d1, inner_k = <ub_k, q>;
  //   ua_{k+1} = (ub_k@M13)∘d2.  k=NIT: dot only (ub_16 never read).
  gemm_k<2><<<grid, 512, 0, stream>>>(vb, Wt + (2 << 20), nullptr, nullptr, h2, nullptr, ua, nullptr, nullptr);
  for (int k = 1; k <= NIT - 1; k++) {
    gemm_k<3><<<grid, 512, 0, stream>>>(ua, Wt + (1 << 20), nullptr, nullptr, h1, ybf, ub, nullptr, inner + (size_t)(k - 1) * BROWS);
    gemm_k<2><<<grid, 512, 0, stream>>>(ub, M13, nullptr, nullptr, h2, nullptr, ua, nullptr, nullptr);
  }
  gemm_k<5><<<grid, 512, 0, stream>>>(ua, Wt + (1 << 20), nullptr, nullptr, h1, ybf, nullptr, nullptr, inner + (size_t)(NIT - 1) * BROWS);

  combine_ldj<<<(BROWS + 255) / 256, 256, 0, stream>>>(ldj, inner, ldj_out);
}